// Round 4
// baseline (1248.570 us; speedup 1.0000x reference)
//
#include <hip/hip_runtime.h>

#define BKT_SHIFT 7            // 128 dst-nodes per bucket
#define BKT_NODES 128
#define NBKT_MAX 800           // >= ceil(100000/128)=782
#define EPB 4096               // edges per block in hist/scatter (256 thr x 16)

// ---- ranked bucket sort (no global atomics) -----------------------------

// Per-block histogram over buckets; hist[blk*NBKT + b] written coalesced.
__global__ void histA(const int* __restrict__ dst, int* __restrict__ hist,
                      int E, int NBKT) {
    __shared__ int lcnt[NBKT_MAX];
    int t = threadIdx.x, blk = blockIdx.x;
    for (int b = t; b < NBKT; b += 256) lcnt[b] = 0;
    __syncthreads();
    int e0 = blk * EPB;
    #pragma unroll
    for (int i = 0; i < 16; ++i) {
        int e = e0 + i * 256 + t;
        if (e < E) atomicAdd(&lcnt[dst[e] >> BKT_SHIFT], 1);
    }
    __syncthreads();
    for (int b = t; b < NBKT; b += 256) hist[blk * NBKT + b] = lcnt[b];
}

// One block per bucket: exclusive scan of hist column b over NBLK blocks
// (in place), total -> T[b]. NBLK <= 1024 (256 thr x 4).
__global__ void colscan(int* __restrict__ hist, int* __restrict__ T,
                        int NBLK, int NBKT) {
    __shared__ int lds[256];
    int b = blockIdx.x, t = threadIdx.x;
    int j0 = t * 4;
    int v0 = (j0 + 0 < NBLK) ? hist[(j0 + 0) * NBKT + b] : 0;
    int v1 = (j0 + 1 < NBLK) ? hist[(j0 + 1) * NBKT + b] : 0;
    int v2 = (j0 + 2 < NBLK) ? hist[(j0 + 2) * NBKT + b] : 0;
    int v3 = (j0 + 3 < NBLK) ? hist[(j0 + 3) * NBKT + b] : 0;
    lds[t] = v0 + v1 + v2 + v3;
    __syncthreads();
    for (int off = 1; off < 256; off <<= 1) {
        int add = (t >= off) ? lds[t - off] : 0;
        __syncthreads();
        lds[t] += add;
        __syncthreads();
    }
    int p = (t == 0) ? 0 : lds[t - 1];
    if (j0 + 0 < NBLK) hist[(j0 + 0) * NBKT + b] = p;  p += v0;
    if (j0 + 1 < NBLK) hist[(j0 + 1) * NBKT + b] = p;  p += v1;
    if (j0 + 2 < NBLK) hist[(j0 + 2) * NBKT + b] = p;  p += v2;
    if (j0 + 3 < NBLK) hist[(j0 + 3) * NBKT + b] = p;
    if (t == 255) T[b] = lds[255];
}

// Single block: exclusive scan of M (<=4096) ints, out[M] = E.
__global__ void scan_small(const int* __restrict__ in, int* __restrict__ out,
                           int M, int E) {
    __shared__ int lds[1024];
    int t = threadIdx.x;
    int base = t * 4;
    int v0 = (base + 0 < M) ? in[base + 0] : 0;
    int v1 = (base + 1 < M) ? in[base + 1] : 0;
    int v2 = (base + 2 < M) ? in[base + 2] : 0;
    int v3 = (base + 3 < M) ? in[base + 3] : 0;
    lds[t] = v0 + v1 + v2 + v3;
    __syncthreads();
    for (int off = 1; off < 1024; off <<= 1) {
        int add = (t >= off) ? lds[t - off] : 0;
        __syncthreads();
        lds[t] += add;
        __syncthreads();
    }
    int p = (t == 0) ? 0 : lds[t - 1];
    if (base + 0 < M) out[base + 0] = p;  p += v0;
    if (base + 1 < M) out[base + 1] = p;  p += v1;
    if (base + 2 < M) out[base + 2] = p;  p += v2;
    if (base + 3 < M) out[base + 3] = p;
    if (t == 0) out[M] = E;
}

// Rank via LDS atomics; write packed (dl<<24)|src into bucket runs
// (~5 consecutive slots per (block,bucket) => line-coalesced scatter).
__global__ void scatter_kernel(const int* __restrict__ src, const int* __restrict__ dst,
                               const int* __restrict__ hist, const int* __restrict__ Tscan,
                               int* __restrict__ staged, int E, int NBKT) {
    __shared__ int lbase[NBKT_MAX];
    __shared__ int lcur[NBKT_MAX];
    int t = threadIdx.x, blk = blockIdx.x;
    for (int b = t; b < NBKT; b += 256) {
        lbase[b] = hist[blk * NBKT + b] + Tscan[b];
        lcur[b] = 0;
    }
    __syncthreads();
    int e0 = blk * EPB;
    #pragma unroll
    for (int i = 0; i < 16; ++i) {
        int e = e0 + i * 256 + t;
        if (e < E) {
            int d = dst[e], s = src[e];
            int b = d >> BKT_SHIFT;
            int r = atomicAdd(&lcur[b], 1);
            staged[lbase[b] + r] = ((d & (BKT_NODES - 1)) << 24) | s;
        }
    }
}

// ---- bucket aggregate + MLP --------------------------------------------
// One block per bucket (128 nodes). Edge phase: 8 edge-streams (half-waves),
// 8-deep gather batching, ds_add_f32 into acc[128][32] (stride 33: edge-phase
// banks (dl+c)%32 distinct per lane; MLP-phase reads conflict-free).
// MLP phase: 16 rounds x 8 node-slots x 32 ch, intra-half-wave LDS sharing.

template <bool RELU_OUT>
__global__ void agg_bucket(const float* __restrict__ xin, const int* __restrict__ staged,
                           const int* __restrict__ Tscan,
                           const float* __restrict__ Wa, const float* __restrict__ ba,
                           const float* __restrict__ Wb, const float* __restrict__ bb,
                           float* __restrict__ out, int N) {
    __shared__ float acc[BKT_NODES * 33];
    __shared__ float sWa[32 * 16];
    __shared__ float sWb[16 * 32];
    __shared__ float sba[16], sbb[32];
    __shared__ float st1[8 * 17];

    int t = threadIdx.x, b = blockIdx.x;
    sWa[t] = Wa[t];  sWa[t + 256] = Wa[t + 256];
    sWb[t] = Wb[t];  sWb[t + 256] = Wb[t + 256];
    if (t < 16) sba[t] = ba[t];
    if (t < 32) sbb[t] = bb[t];
    for (int i = t; i < BKT_NODES * 33; i += 256) acc[i] = 0.f;
    __syncthreads();

    int e0 = Tscan[b], e1 = Tscan[b + 1];
    int m = e1 - e0;
    int stream = t >> 5, c = t & 31;
    int len = (m + 7) >> 3;
    int cs = e0 + stream * len;
    int ce = min(cs + len, e1);
    int k = cs;
    for (; k + 8 <= ce; k += 8) {
        int v0 = staged[k + 0], v1 = staged[k + 1], v2 = staged[k + 2], v3 = staged[k + 3];
        int v4 = staged[k + 4], v5 = staged[k + 5], v6 = staged[k + 6], v7 = staged[k + 7];
        float a0 = xin[(size_t)(v0 & 0xFFFFFF) * 32 + c];
        float a1 = xin[(size_t)(v1 & 0xFFFFFF) * 32 + c];
        float a2 = xin[(size_t)(v2 & 0xFFFFFF) * 32 + c];
        float a3 = xin[(size_t)(v3 & 0xFFFFFF) * 32 + c];
        float a4 = xin[(size_t)(v4 & 0xFFFFFF) * 32 + c];
        float a5 = xin[(size_t)(v5 & 0xFFFFFF) * 32 + c];
        float a6 = xin[(size_t)(v6 & 0xFFFFFF) * 32 + c];
        float a7 = xin[(size_t)(v7 & 0xFFFFFF) * 32 + c];
        atomicAdd(&acc[(((unsigned)v0) >> 24) * 33 + c], a0);
        atomicAdd(&acc[(((unsigned)v1) >> 24) * 33 + c], a1);
        atomicAdd(&acc[(((unsigned)v2) >> 24) * 33 + c], a2);
        atomicAdd(&acc[(((unsigned)v3) >> 24) * 33 + c], a3);
        atomicAdd(&acc[(((unsigned)v4) >> 24) * 33 + c], a4);
        atomicAdd(&acc[(((unsigned)v5) >> 24) * 33 + c], a5);
        atomicAdd(&acc[(((unsigned)v6) >> 24) * 33 + c], a6);
        atomicAdd(&acc[(((unsigned)v7) >> 24) * 33 + c], a7);
    }
    for (; k < ce; ++k) {
        int v = staged[k];
        float a = xin[(size_t)(v & 0xFFFFFF) * 32 + c];
        atomicAdd(&acc[(((unsigned)v) >> 24) * 33 + c], a);
    }
    __syncthreads();

    int n0 = b << BKT_SHIFT;
    int ln = t >> 5;
    for (int r = 0; r < 16; ++r) {
        int node = r * 8 + ln;
        int n = n0 + node;
        if (n < N) {
            float v = acc[node * 33 + c] + xin[(size_t)n * 32 + c];  // self (eps=0)
            acc[node * 33 + c] = v;                 // share within half-wave
            if (c < 16) {
                float tacc = sba[c];
                #pragma unroll
                for (int cc = 0; cc < 32; ++cc) tacc += acc[node * 33 + cc] * sWa[cc * 16 + c];
                st1[ln * 17 + c] = fmaxf(tacc, 0.f);
            }
            float o = sbb[c];
            #pragma unroll
            for (int j = 0; j < 16; ++j) o += st1[ln * 17 + j] * sWb[j * 32 + c];
            out[(size_t)n * 32 + c] = RELU_OUT ? fmaxf(o, 0.f) : o;
        }
    }
}

// ---- Launch -------------------------------------------------------------

extern "C" void kernel_launch(void* const* d_in, const int* in_sizes, int n_in,
                              void* d_out, int out_size, void* d_ws, size_t ws_size,
                              hipStream_t stream) {
    const float* x  = (const float*)d_in[0];
    const int*   ei = (const int*)d_in[1];
    const float* W1 = (const float*)d_in[2];
    const float* b1 = (const float*)d_in[3];
    const float* W2 = (const float*)d_in[4];
    const float* b2 = (const float*)d_in[5];
    const float* W3 = (const float*)d_in[6];
    const float* b3 = (const float*)d_in[7];
    const float* W4 = (const float*)d_in[8];
    const float* b4 = (const float*)d_in[9];

    const int N = in_sizes[0] / 32;
    const int E = in_sizes[1] / 2;
    const int* src = ei;
    const int* dst = ei + E;

    const int NBKT = (N + BKT_NODES - 1) >> BKT_SHIFT;   // 782
    const int NBLK = (E + EPB - 1) / EPB;                // 611 (<=1024 for colscan)

    char* ws = (char*)d_ws;
    size_t o = 0;
    auto alloc = [&](size_t bytes) -> char* {
        o = (o + 255) & ~(size_t)255;
        char* r = ws + o;
        o += bytes;
        return r;
    };
    int*   hist   = (int*)  alloc(4 * (size_t)NBLK * NBKT);
    int*   T      = (int*)  alloc(4 * (size_t)NBKT);
    int*   Tscan  = (int*)  alloc(4 * (size_t)(NBKT + 1));
    int*   staged = (int*)  alloc(4 * (size_t)E);
    float* h      = (float*)alloc(4 * (size_t)N * 32);

    histA<<<NBLK, 256, 0, stream>>>(dst, hist, E, NBKT);
    colscan<<<NBKT, 256, 0, stream>>>(hist, T, NBLK, NBKT);
    scan_small<<<1, 1024, 0, stream>>>(T, Tscan, NBKT, E);
    scatter_kernel<<<NBLK, 256, 0, stream>>>(src, dst, hist, Tscan, staged, E, NBKT);

    agg_bucket<true ><<<NBKT, 256, 0, stream>>>(x, staged, Tscan, W1, b1, W2, b2, h, N);
    agg_bucket<false><<<NBKT, 256, 0, stream>>>(h, staged, Tscan, W3, b3, W4, b4,
                                                (float*)d_out, N);
}

// Round 5
// 267.032 us; speedup vs baseline: 4.6757x; 4.6757x over previous
//
#include <hip/hip_runtime.h>

#define BKT_SHIFT 7            // 128 dst-nodes per bucket
#define BKT_NODES 128
#define NBKT_MAX 800           // >= ceil(100000/128)=782
#define EPB 4096               // edges per block in hist/scatter (256 thr x 16)
#define SCOL_CAP 8192          // LDS col staging in fine_fill (32 KB); mean bucket = 3200

// ---- ranked bucket sort (no global atomics) -----------------------------

__global__ void histA(const int* __restrict__ dst, int* __restrict__ hist,
                      int E, int NBKT) {
    __shared__ int lcnt[NBKT_MAX];
    int t = threadIdx.x, blk = blockIdx.x;
    for (int b = t; b < NBKT; b += 256) lcnt[b] = 0;
    __syncthreads();
    int e0 = blk * EPB;
    #pragma unroll
    for (int i = 0; i < 16; ++i) {
        int e = e0 + i * 256 + t;
        if (e < E) atomicAdd(&lcnt[dst[e] >> BKT_SHIFT], 1);
    }
    __syncthreads();
    for (int b = t; b < NBKT; b += 256) hist[blk * NBKT + b] = lcnt[b];
}

// One block per bucket: exclusive scan of hist column b over NBLK blocks
// (in place), total -> T[b]. NBLK <= 1024 (256 thr x 4).
__global__ void colscan(int* __restrict__ hist, int* __restrict__ T,
                        int NBLK, int NBKT) {
    __shared__ int lds[256];
    int b = blockIdx.x, t = threadIdx.x;
    int j0 = t * 4;
    int v0 = (j0 + 0 < NBLK) ? hist[(j0 + 0) * NBKT + b] : 0;
    int v1 = (j0 + 1 < NBLK) ? hist[(j0 + 1) * NBKT + b] : 0;
    int v2 = (j0 + 2 < NBLK) ? hist[(j0 + 2) * NBKT + b] : 0;
    int v3 = (j0 + 3 < NBLK) ? hist[(j0 + 3) * NBKT + b] : 0;
    lds[t] = v0 + v1 + v2 + v3;
    __syncthreads();
    for (int off = 1; off < 256; off <<= 1) {
        int add = (t >= off) ? lds[t - off] : 0;
        __syncthreads();
        lds[t] += add;
        __syncthreads();
    }
    int p = (t == 0) ? 0 : lds[t - 1];
    if (j0 + 0 < NBLK) hist[(j0 + 0) * NBKT + b] = p;  p += v0;
    if (j0 + 1 < NBLK) hist[(j0 + 1) * NBKT + b] = p;  p += v1;
    if (j0 + 2 < NBLK) hist[(j0 + 2) * NBKT + b] = p;  p += v2;
    if (j0 + 3 < NBLK) hist[(j0 + 3) * NBKT + b] = p;
    if (t == 255) T[b] = lds[255];
}

// Single block: exclusive scan of M (<=4096) ints, out[M] = E.
__global__ void scan_small(const int* __restrict__ in, int* __restrict__ out,
                           int M, int E) {
    __shared__ int lds[1024];
    int t = threadIdx.x;
    int base = t * 4;
    int v0 = (base + 0 < M) ? in[base + 0] : 0;
    int v1 = (base + 1 < M) ? in[base + 1] : 0;
    int v2 = (base + 2 < M) ? in[base + 2] : 0;
    int v3 = (base + 3 < M) ? in[base + 3] : 0;
    lds[t] = v0 + v1 + v2 + v3;
    __syncthreads();
    for (int off = 1; off < 1024; off <<= 1) {
        int add = (t >= off) ? lds[t - off] : 0;
        __syncthreads();
        lds[t] += add;
        __syncthreads();
    }
    int p = (t == 0) ? 0 : lds[t - 1];
    if (base + 0 < M) out[base + 0] = p;  p += v0;
    if (base + 1 < M) out[base + 1] = p;  p += v1;
    if (base + 2 < M) out[base + 2] = p;  p += v2;
    if (base + 3 < M) out[base + 3] = p;
    if (t == 0) out[M] = E;
}

// Rank via LDS atomics; write packed (dl<<24)|src into bucket runs
// (~6-7 consecutive slots per (block,bucket) => line-coalesced scatter).
__global__ void scatter_kernel(const int* __restrict__ src, const int* __restrict__ dst,
                               const int* __restrict__ hist, const int* __restrict__ Tscan,
                               int* __restrict__ staged, int E, int NBKT) {
    __shared__ int lbase[NBKT_MAX];
    __shared__ int lcur[NBKT_MAX];
    int t = threadIdx.x, blk = blockIdx.x;
    for (int b = t; b < NBKT; b += 256) {
        lbase[b] = hist[blk * NBKT + b] + Tscan[b];
        lcur[b] = 0;
    }
    __syncthreads();
    int e0 = blk * EPB;
    #pragma unroll
    for (int i = 0; i < 16; ++i) {
        int e = e0 + i * 256 + t;
        if (e < E) {
            int d = dst[e], s = src[e];
            int b = d >> BKT_SHIFT;
            int r = atomicAdd(&lcur[b], 1);
            staged[lbase[b] + r] = ((d & (BKT_NODES - 1)) << 24) | s;
        }
    }
}

// One block per bucket: LDS per-node count -> scan (writes rp!) -> LDS place
// -> coalesced col flush. Replaces the global-scatter fill (R2: 157 MB writes).
__global__ void fine_fill(const int* __restrict__ staged, const int* __restrict__ Tscan,
                          int* __restrict__ rp, int* __restrict__ col,
                          int N, int E, int NBKT) {
    __shared__ int scnt[256];   // 128 used; padded to 256 for uniform scan
    __shared__ int srel[256];
    __shared__ int scur[256];
    __shared__ int scol[SCOL_CAP];
    int b = blockIdx.x, t = threadIdx.x;
    int n0 = b << BKT_SHIFT;
    int nn = min(BKT_NODES, N - n0);
    int e0 = Tscan[b];
    int e1 = Tscan[b + 1];
    int m = e1 - e0;

    scnt[t] = 0; scur[t] = 0;
    __syncthreads();
    for (int i = t; i < m; i += 256) {
        int dl = ((unsigned)staged[e0 + i]) >> 24;
        atomicAdd(&scnt[dl], 1);
    }
    __syncthreads();
    int inc_in = scnt[t];
    for (int off = 1; off < 256; off <<= 1) {   // Hillis-Steele inclusive
        int add = (t >= off) ? scnt[t - off] : 0;
        __syncthreads();
        scnt[t] += add;
        __syncthreads();
    }
    int excl = scnt[t] - inc_in;
    srel[t] = excl;
    if (t < nn) rp[n0 + t] = e0 + excl;
    if (b == NBKT - 1 && t == 0) rp[N] = E;
    __syncthreads();

    if (m <= SCOL_CAP) {
        for (int i = t; i < m; i += 256) {
            int v = staged[e0 + i];
            int dl = ((unsigned)v) >> 24;
            int p = srel[dl] + atomicAdd(&scur[dl], 1);
            scol[p] = v & 0xFFFFFF;
        }
        __syncthreads();
        for (int i = t; i < m; i += 256) col[e0 + i] = scol[i];
    } else {  // statistically unreachable overflow fallback
        for (int i = t; i < m; i += 256) {
            int v = staged[e0 + i];
            int dl = ((unsigned)v) >> 24;
            int p = srel[dl] + atomicAdd(&scur[dl], 1);
            col[e0 + p] = v & 0xFFFFFF;
        }
    }
}

// ---- Fused aggregate + MLP (R2 structure: the proven fast one) ----------
// Block = 256 threads = 8 nodes x 32 channels; 8-way unrolled neighbor gather
// for MLP (latency-bound fix), MLP through LDS.

template <bool RELU_OUT>
__global__ void agg_mlp(const float* __restrict__ xin, const int* __restrict__ rp,
                        const int* __restrict__ col,
                        const float* __restrict__ Wa, const float* __restrict__ ba,
                        const float* __restrict__ Wb, const float* __restrict__ bb,
                        float* __restrict__ out, int N) {
    __shared__ float sWa[32 * 16];
    __shared__ float sWb[16 * 32];
    __shared__ float sba[16], sbb[32];
    __shared__ float sv[8][32];
    __shared__ float st1[8][16];

    int t = threadIdx.x;
    sWa[t] = Wa[t];  sWa[t + 256] = Wa[t + 256];
    sWb[t] = Wb[t];  sWb[t + 256] = Wb[t + 256];
    if (t < 16) sba[t] = ba[t];
    if (t < 32) sbb[t] = bb[t];

    int ln = t >> 5;
    int c  = t & 31;
    int n  = blockIdx.x * 8 + ln;
    bool act = (n < N);

    if (act) {
        float v = xin[(size_t)n * 32 + c];
        int ks = rp[n], ke = rp[n + 1];
        int k = ks;
        for (; k + 8 <= ke; k += 8) {
            int s0 = col[k + 0], s1 = col[k + 1], s2 = col[k + 2], s3 = col[k + 3];
            int s4 = col[k + 4], s5 = col[k + 5], s6 = col[k + 6], s7 = col[k + 7];
            float a0 = xin[(size_t)s0 * 32 + c];
            float a1 = xin[(size_t)s1 * 32 + c];
            float a2 = xin[(size_t)s2 * 32 + c];
            float a3 = xin[(size_t)s3 * 32 + c];
            float a4 = xin[(size_t)s4 * 32 + c];
            float a5 = xin[(size_t)s5 * 32 + c];
            float a6 = xin[(size_t)s6 * 32 + c];
            float a7 = xin[(size_t)s7 * 32 + c];
            v += ((a0 + a1) + (a2 + a3)) + ((a4 + a5) + (a6 + a7));
        }
        for (; k < ke; ++k) v += xin[(size_t)col[k] * 32 + c];
        sv[ln][c] = v;
    }
    __syncthreads();

    if (act && c < 16) {
        float tacc = sba[c];
        #pragma unroll
        for (int cc = 0; cc < 32; ++cc) tacc += sv[ln][cc] * sWa[cc * 16 + c];
        st1[ln][c] = fmaxf(tacc, 0.f);
    }
    __syncthreads();

    if (act) {
        float acc = sbb[c];
        #pragma unroll
        for (int j = 0; j < 16; ++j) acc += st1[ln][j] * sWb[j * 32 + c];
        out[(size_t)n * 32 + c] = RELU_OUT ? fmaxf(acc, 0.f) : acc;
    }
}

// ---- Launch -------------------------------------------------------------

extern "C" void kernel_launch(void* const* d_in, const int* in_sizes, int n_in,
                              void* d_out, int out_size, void* d_ws, size_t ws_size,
                              hipStream_t stream) {
    const float* x  = (const float*)d_in[0];
    const int*   ei = (const int*)d_in[1];
    const float* W1 = (const float*)d_in[2];
    const float* b1 = (const float*)d_in[3];
    const float* W2 = (const float*)d_in[4];
    const float* b2 = (const float*)d_in[5];
    const float* W3 = (const float*)d_in[6];
    const float* b3 = (const float*)d_in[7];
    const float* W4 = (const float*)d_in[8];
    const float* b4 = (const float*)d_in[9];

    const int N = in_sizes[0] / 32;
    const int E = in_sizes[1] / 2;
    const int* src = ei;
    const int* dst = ei + E;

    const int NBKT = (N + BKT_NODES - 1) >> BKT_SHIFT;   // 782
    const int NBLK = (E + EPB - 1) / EPB;                // 611 (<=1024 for colscan)

    char* ws = (char*)d_ws;
    size_t o = 0;
    auto alloc = [&](size_t bytes) -> char* {
        o = (o + 255) & ~(size_t)255;
        char* r = ws + o;
        o += bytes;
        return r;
    };
    int*   hist   = (int*)  alloc(4 * (size_t)NBLK * NBKT);
    int*   T      = (int*)  alloc(4 * (size_t)NBKT);
    int*   Tscan  = (int*)  alloc(4 * (size_t)(NBKT + 1));
    int*   staged = (int*)  alloc(4 * (size_t)E);
    int*   rp     = (int*)  alloc(4 * (size_t)(N + 1));
    int*   col    = (int*)  alloc(4 * (size_t)E);
    float* h      = (float*)alloc(4 * (size_t)N * 32);

    histA<<<NBLK, 256, 0, stream>>>(dst, hist, E, NBKT);
    colscan<<<NBKT, 256, 0, stream>>>(hist, T, NBLK, NBKT);
    scan_small<<<1, 1024, 0, stream>>>(T, Tscan, NBKT, E);
    scatter_kernel<<<NBLK, 256, 0, stream>>>(src, dst, hist, Tscan, staged, E, NBKT);
    fine_fill<<<NBKT, 256, 0, stream>>>(staged, Tscan, rp, col, N, E, NBKT);

    agg_mlp<true ><<<(N + 7) / 8, 256, 0, stream>>>(x, rp, col, W1, b1, W2, b2, h, N);
    agg_mlp<false><<<(N + 7) / 8, 256, 0, stream>>>(h, rp, col, W3, b3, W4, b4,
                                                    (float*)d_out, N);
}

// Round 6
// 257.203 us; speedup vs baseline: 4.8544x; 1.0382x over previous
//
#include <hip/hip_runtime.h>

typedef unsigned short ushort_t;

#define BKT_SHIFT 7            // 128 dst-nodes per bucket
#define BKT_NODES 128
#define NBKT_MAX 800           // >= ceil(100000/128)=782
#define EPB 8192               // edges per block in hist/scatter (512 thr x 16)
#define SCOL_CAP 8192          // LDS col staging in fine_fill (32 KB); mean bucket = 3200

__device__ __forceinline__ ushort_t f2bf(float f) {
    unsigned u = __float_as_uint(f);
    unsigned r = (u + 0x7FFFu + ((u >> 16) & 1u)) >> 16;   // RNE
    return (ushort_t)r;
}
__device__ __forceinline__ float bf2f(ushort_t b) {
    return __uint_as_float(((unsigned)b) << 16);
}

// ---- x -> bf16 ----------------------------------------------------------
__global__ void to_bf16(const float4* __restrict__ in, ushort_t* __restrict__ out, int n4) {
    int i = blockIdx.x * blockDim.x + threadIdx.x;
    if (i < n4) {
        float4 v = in[i];
        out[i * 4 + 0] = f2bf(v.x);
        out[i * 4 + 1] = f2bf(v.y);
        out[i * 4 + 2] = f2bf(v.z);
        out[i * 4 + 3] = f2bf(v.w);
    }
}

// ---- ranked bucket sort (no global atomics) -----------------------------

__global__ void histA(const int* __restrict__ dst, int* __restrict__ hist,
                      int E, int NBKT) {
    __shared__ int lcnt[NBKT_MAX];
    int t = threadIdx.x, blk = blockIdx.x;
    for (int b = t; b < NBKT; b += 512) lcnt[b] = 0;
    __syncthreads();
    int e0 = blk * EPB;
    #pragma unroll
    for (int i = 0; i < 16; ++i) {
        int e = e0 + i * 512 + t;
        if (e < E) atomicAdd(&lcnt[dst[e] >> BKT_SHIFT], 1);
    }
    __syncthreads();
    for (int b = t; b < NBKT; b += 512) hist[blk * NBKT + b] = lcnt[b];
}

// One block per bucket: exclusive scan of hist column b over NBLK blocks
// (in place), total -> T[b]. NBLK <= 1024 (256 thr x 4).
__global__ void colscan(int* __restrict__ hist, int* __restrict__ T,
                        int NBLK, int NBKT) {
    __shared__ int lds[256];
    int b = blockIdx.x, t = threadIdx.x;
    int j0 = t * 4;
    int v0 = (j0 + 0 < NBLK) ? hist[(j0 + 0) * NBKT + b] : 0;
    int v1 = (j0 + 1 < NBLK) ? hist[(j0 + 1) * NBKT + b] : 0;
    int v2 = (j0 + 2 < NBLK) ? hist[(j0 + 2) * NBKT + b] : 0;
    int v3 = (j0 + 3 < NBLK) ? hist[(j0 + 3) * NBKT + b] : 0;
    lds[t] = v0 + v1 + v2 + v3;
    __syncthreads();
    for (int off = 1; off < 256; off <<= 1) {
        int add = (t >= off) ? lds[t - off] : 0;
        __syncthreads();
        lds[t] += add;
        __syncthreads();
    }
    int p = (t == 0) ? 0 : lds[t - 1];
    if (j0 + 0 < NBLK) hist[(j0 + 0) * NBKT + b] = p;  p += v0;
    if (j0 + 1 < NBLK) hist[(j0 + 1) * NBKT + b] = p;  p += v1;
    if (j0 + 2 < NBLK) hist[(j0 + 2) * NBKT + b] = p;  p += v2;
    if (j0 + 3 < NBLK) hist[(j0 + 3) * NBKT + b] = p;
    if (t == 255) T[b] = lds[255];
}

// Single block: exclusive scan of M (<=4096) ints, out[M] = E.
__global__ void scan_small(const int* __restrict__ in, int* __restrict__ out,
                           int M, int E) {
    __shared__ int lds[1024];
    int t = threadIdx.x;
    int base = t * 4;
    int v0 = (base + 0 < M) ? in[base + 0] : 0;
    int v1 = (base + 1 < M) ? in[base + 1] : 0;
    int v2 = (base + 2 < M) ? in[base + 2] : 0;
    int v3 = (base + 3 < M) ? in[base + 3] : 0;
    lds[t] = v0 + v1 + v2 + v3;
    __syncthreads();
    for (int off = 1; off < 1024; off <<= 1) {
        int add = (t >= off) ? lds[t - off] : 0;
        __syncthreads();
        lds[t] += add;
        __syncthreads();
    }
    int p = (t == 0) ? 0 : lds[t - 1];
    if (base + 0 < M) out[base + 0] = p;  p += v0;
    if (base + 1 < M) out[base + 1] = p;  p += v1;
    if (base + 2 < M) out[base + 2] = p;  p += v2;
    if (base + 3 < M) out[base + 3] = p;
    if (t == 0) out[M] = E;
}

// Rank via LDS atomics; write packed (dl<<24)|src into bucket runs
// (~10.5 consecutive slots per (block,bucket) => line-coalesced scatter).
__global__ void scatter_kernel(const int* __restrict__ src, const int* __restrict__ dst,
                               const int* __restrict__ hist, const int* __restrict__ Tscan,
                               int* __restrict__ staged, int E, int NBKT) {
    __shared__ int lbase[NBKT_MAX];
    __shared__ int lcur[NBKT_MAX];
    int t = threadIdx.x, blk = blockIdx.x;
    for (int b = t; b < NBKT; b += 512) {
        lbase[b] = hist[blk * NBKT + b] + Tscan[b];
        lcur[b] = 0;
    }
    __syncthreads();
    int e0 = blk * EPB;
    #pragma unroll
    for (int i = 0; i < 16; ++i) {
        int e = e0 + i * 512 + t;
        if (e < E) {
            int d = dst[e], s = src[e];
            int b = d >> BKT_SHIFT;
            int r = atomicAdd(&lcur[b], 1);
            staged[lbase[b] + r] = ((d & (BKT_NODES - 1)) << 24) | s;
        }
    }
}

// One block per bucket: LDS per-node count -> scan (writes rp!) -> LDS place
// -> coalesced col flush.
__global__ void fine_fill(const int* __restrict__ staged, const int* __restrict__ Tscan,
                          int* __restrict__ rp, int* __restrict__ col,
                          int N, int E, int NBKT) {
    __shared__ int scnt[256];   // 128 used; padded to 256 for uniform scan
    __shared__ int srel[256];
    __shared__ int scur[256];
    __shared__ int scol[SCOL_CAP];
    int b = blockIdx.x, t = threadIdx.x;
    int n0 = b << BKT_SHIFT;
    int nn = min(BKT_NODES, N - n0);
    int e0 = Tscan[b];
    int e1 = Tscan[b + 1];
    int m = e1 - e0;

    scnt[t] = 0; scur[t] = 0;
    __syncthreads();
    for (int i = t; i < m; i += 256) {
        int dl = ((unsigned)staged[e0 + i]) >> 24;
        atomicAdd(&scnt[dl], 1);
    }
    __syncthreads();
    int inc_in = scnt[t];
    for (int off = 1; off < 256; off <<= 1) {   // Hillis-Steele inclusive
        int add = (t >= off) ? scnt[t - off] : 0;
        __syncthreads();
        scnt[t] += add;
        __syncthreads();
    }
    int excl = scnt[t] - inc_in;
    srel[t] = excl;
    if (t < nn) rp[n0 + t] = e0 + excl;
    if (b == NBKT - 1 && t == 0) rp[N] = E;
    __syncthreads();

    if (m <= SCOL_CAP) {
        for (int i = t; i < m; i += 256) {
            int v = staged[e0 + i];
            int dl = ((unsigned)v) >> 24;
            int p = srel[dl] + atomicAdd(&scur[dl], 1);
            scol[p] = v & 0xFFFFFF;
        }
        __syncthreads();
        for (int i = t; i < m; i += 256) col[e0 + i] = scol[i];
    } else {  // statistically unreachable overflow fallback
        for (int i = t; i < m; i += 256) {
            int v = staged[e0 + i];
            int dl = ((unsigned)v) >> 24;
            int p = srel[dl] + atomicAdd(&scur[dl], 1);
            col[e0 + p] = v & 0xFFFFFF;
        }
    }
}

// ---- Fused aggregate + MLP ---------------------------------------------
// Block = 256 threads = 8 nodes x 32 channels; 8-way unrolled neighbor gather.
// Input rows are bf16 (64 B = 1 cache line per gather; R5 was 128 B = 2 lines).
// Accumulation + MLP in fp32. Conv1 emits bf16 h; conv2 emits fp32 d_out.

template <bool RELU_OUT, bool OUT_BF16>
__global__ void agg_mlp(const ushort_t* __restrict__ xin, const int* __restrict__ rp,
                        const int* __restrict__ col,
                        const float* __restrict__ Wa, const float* __restrict__ ba,
                        const float* __restrict__ Wb, const float* __restrict__ bb,
                        void* __restrict__ outv, int N) {
    __shared__ float sWa[32 * 16];
    __shared__ float sWb[16 * 32];
    __shared__ float sba[16], sbb[32];
    __shared__ float sv[8][32];
    __shared__ float st1[8][16];

    int t = threadIdx.x;
    sWa[t] = Wa[t];  sWa[t + 256] = Wa[t + 256];
    sWb[t] = Wb[t];  sWb[t + 256] = Wb[t + 256];
    if (t < 16) sba[t] = ba[t];
    if (t < 32) sbb[t] = bb[t];

    int ln = t >> 5;
    int c  = t & 31;
    int n  = blockIdx.x * 8 + ln;
    bool act = (n < N);

    if (act) {
        float v = bf2f(xin[(size_t)n * 32 + c]);
        int ks = rp[n], ke = rp[n + 1];
        int k = ks;
        for (; k + 8 <= ke; k += 8) {
            int s0 = col[k + 0], s1 = col[k + 1], s2 = col[k + 2], s3 = col[k + 3];
            int s4 = col[k + 4], s5 = col[k + 5], s6 = col[k + 6], s7 = col[k + 7];
            ushort_t a0 = xin[(size_t)s0 * 32 + c];
            ushort_t a1 = xin[(size_t)s1 * 32 + c];
            ushort_t a2 = xin[(size_t)s2 * 32 + c];
            ushort_t a3 = xin[(size_t)s3 * 32 + c];
            ushort_t a4 = xin[(size_t)s4 * 32 + c];
            ushort_t a5 = xin[(size_t)s5 * 32 + c];
            ushort_t a6 = xin[(size_t)s6 * 32 + c];
            ushort_t a7 = xin[(size_t)s7 * 32 + c];
            v += ((bf2f(a0) + bf2f(a1)) + (bf2f(a2) + bf2f(a3)))
               + ((bf2f(a4) + bf2f(a5)) + (bf2f(a6) + bf2f(a7)));
        }
        for (; k < ke; ++k) v += bf2f(xin[(size_t)col[k] * 32 + c]);
        sv[ln][c] = v;
    }
    __syncthreads();

    if (act && c < 16) {
        float tacc = sba[c];
        #pragma unroll
        for (int cc = 0; cc < 32; ++cc) tacc += sv[ln][cc] * sWa[cc * 16 + c];
        st1[ln][c] = fmaxf(tacc, 0.f);
    }
    __syncthreads();

    if (act) {
        float acc = sbb[c];
        #pragma unroll
        for (int j = 0; j < 16; ++j) acc += st1[ln][j] * sWb[j * 32 + c];
        if (RELU_OUT) acc = fmaxf(acc, 0.f);
        if (OUT_BF16) ((ushort_t*)outv)[(size_t)n * 32 + c] = f2bf(acc);
        else          ((float*)outv)[(size_t)n * 32 + c] = acc;
    }
}

// ---- Launch -------------------------------------------------------------

extern "C" void kernel_launch(void* const* d_in, const int* in_sizes, int n_in,
                              void* d_out, int out_size, void* d_ws, size_t ws_size,
                              hipStream_t stream) {
    const float* x  = (const float*)d_in[0];
    const int*   ei = (const int*)d_in[1];
    const float* W1 = (const float*)d_in[2];
    const float* b1 = (const float*)d_in[3];
    const float* W2 = (const float*)d_in[4];
    const float* b2 = (const float*)d_in[5];
    const float* W3 = (const float*)d_in[6];
    const float* b3 = (const float*)d_in[7];
    const float* W4 = (const float*)d_in[8];
    const float* b4 = (const float*)d_in[9];

    const int N = in_sizes[0] / 32;
    const int E = in_sizes[1] / 2;
    const int* src = ei;
    const int* dst = ei + E;

    const int NBKT = (N + BKT_NODES - 1) >> BKT_SHIFT;   // 782
    const int NBLK = (E + EPB - 1) / EPB;                // 306 (<=1024 for colscan)

    char* ws = (char*)d_ws;
    size_t o = 0;
    auto alloc = [&](size_t bytes) -> char* {
        o = (o + 255) & ~(size_t)255;
        char* r = ws + o;
        o += bytes;
        return r;
    };
    int*      hist   = (int*)     alloc(4 * (size_t)NBLK * NBKT);
    int*      T      = (int*)     alloc(4 * (size_t)NBKT);
    int*      Tscan  = (int*)     alloc(4 * (size_t)(NBKT + 1));
    int*      staged = (int*)     alloc(4 * (size_t)E);
    int*      rp     = (int*)     alloc(4 * (size_t)(N + 1));
    int*      col    = (int*)     alloc(4 * (size_t)E);
    ushort_t* xb     = (ushort_t*)alloc(2 * (size_t)N * 32);
    ushort_t* hb     = (ushort_t*)alloc(2 * (size_t)N * 32);

    int n4 = N * 32 / 4;
    to_bf16<<<(n4 + 255) / 256, 256, 0, stream>>>((const float4*)x, xb, n4);

    histA<<<NBLK, 512, 0, stream>>>(dst, hist, E, NBKT);
    colscan<<<NBKT, 256, 0, stream>>>(hist, T, NBLK, NBKT);
    scan_small<<<1, 1024, 0, stream>>>(T, Tscan, NBKT, E);
    scatter_kernel<<<NBLK, 512, 0, stream>>>(src, dst, hist, Tscan, staged, E, NBKT);
    fine_fill<<<NBKT, 256, 0, stream>>>(staged, Tscan, rp, col, N, E, NBKT);

    agg_mlp<true,  true ><<<(N + 7) / 8, 256, 0, stream>>>(xb, rp, col, W1, b1, W2, b2, hb, N);
    agg_mlp<false, false><<<(N + 7) / 8, 256, 0, stream>>>(hb, rp, col, W3, b3, W4, b4,
                                                           d_out, N);
}

// Round 7
// 223.578 us; speedup vs baseline: 5.5845x; 1.1504x over previous
//
#include <hip/hip_runtime.h>

typedef unsigned short ushort_t;
typedef unsigned int uint_t;

#define BKT_SHIFT 7            // 128 dst-nodes per bucket
#define BKT_NODES 128
#define NBKT_MAX 800           // >= ceil(100000/128)=782
#define EPB 16384              // edges per block in hist/scatter (512 thr x 32)
#define SCOL_CAP 8192          // LDS col staging in fine_fill (32 KB); mean bucket = 3200
#define NPB 16                 // nodes per block in agg_mlp
#define SCOL_N 768             // LDS col cache per agg block (mean 400, Poisson tail safe)

__device__ __forceinline__ ushort_t f2bf(float f) {
    unsigned u = __float_as_uint(f);
    unsigned r = (u + 0x7FFFu + ((u >> 16) & 1u)) >> 16;   // RNE
    return (ushort_t)r;
}

// ---- x -> bf16 ----------------------------------------------------------
__global__ void to_bf16(const float4* __restrict__ in, ushort_t* __restrict__ out, int n4) {
    int i = blockIdx.x * blockDim.x + threadIdx.x;
    if (i < n4) {
        float4 v = in[i];
        out[i * 4 + 0] = f2bf(v.x);
        out[i * 4 + 1] = f2bf(v.y);
        out[i * 4 + 2] = f2bf(v.z);
        out[i * 4 + 3] = f2bf(v.w);
    }
}

// ---- ranked bucket sort (no global atomics) -----------------------------

__global__ void histA(const int* __restrict__ dst, int* __restrict__ hist,
                      int E, int NBKT) {
    __shared__ int lcnt[NBKT_MAX];
    int t = threadIdx.x, blk = blockIdx.x;
    for (int b = t; b < NBKT; b += 512) lcnt[b] = 0;
    __syncthreads();
    int e0 = blk * EPB;
    #pragma unroll
    for (int i = 0; i < 32; ++i) {
        int e = e0 + i * 512 + t;
        if (e < E) atomicAdd(&lcnt[dst[e] >> BKT_SHIFT], 1);
    }
    __syncthreads();
    for (int b = t; b < NBKT; b += 512) hist[blk * NBKT + b] = lcnt[b];
}

// One block per bucket: exclusive scan of hist column b over NBLK blocks
// (in place), total -> T[b]. NBLK <= 1024 (256 thr x 4).
__global__ void colscan(int* __restrict__ hist, int* __restrict__ T,
                        int NBLK, int NBKT) {
    __shared__ int lds[256];
    int b = blockIdx.x, t = threadIdx.x;
    int j0 = t * 4;
    int v0 = (j0 + 0 < NBLK) ? hist[(j0 + 0) * NBKT + b] : 0;
    int v1 = (j0 + 1 < NBLK) ? hist[(j0 + 1) * NBKT + b] : 0;
    int v2 = (j0 + 2 < NBLK) ? hist[(j0 + 2) * NBKT + b] : 0;
    int v3 = (j0 + 3 < NBLK) ? hist[(j0 + 3) * NBKT + b] : 0;
    lds[t] = v0 + v1 + v2 + v3;
    __syncthreads();
    for (int off = 1; off < 256; off <<= 1) {
        int add = (t >= off) ? lds[t - off] : 0;
        __syncthreads();
        lds[t] += add;
        __syncthreads();
    }
    int p = (t == 0) ? 0 : lds[t - 1];
    if (j0 + 0 < NBLK) hist[(j0 + 0) * NBKT + b] = p;  p += v0;
    if (j0 + 1 < NBLK) hist[(j0 + 1) * NBKT + b] = p;  p += v1;
    if (j0 + 2 < NBLK) hist[(j0 + 2) * NBKT + b] = p;  p += v2;
    if (j0 + 3 < NBLK) hist[(j0 + 3) * NBKT + b] = p;
    if (t == 255) T[b] = lds[255];
}

// Single block: exclusive scan of M (<=4096) ints, out[M] = E.
__global__ void scan_small(const int* __restrict__ in, int* __restrict__ out,
                           int M, int E) {
    __shared__ int lds[1024];
    int t = threadIdx.x;
    int base = t * 4;
    int v0 = (base + 0 < M) ? in[base + 0] : 0;
    int v1 = (base + 1 < M) ? in[base + 1] : 0;
    int v2 = (base + 2 < M) ? in[base + 2] : 0;
    int v3 = (base + 3 < M) ? in[base + 3] : 0;
    lds[t] = v0 + v1 + v2 + v3;
    __syncthreads();
    for (int off = 1; off < 1024; off <<= 1) {
        int add = (t >= off) ? lds[t - off] : 0;
        __syncthreads();
        lds[t] += add;
        __syncthreads();
    }
    int p = (t == 0) ? 0 : lds[t - 1];
    if (base + 0 < M) out[base + 0] = p;  p += v0;
    if (base + 1 < M) out[base + 1] = p;  p += v1;
    if (base + 2 < M) out[base + 2] = p;  p += v2;
    if (base + 3 < M) out[base + 3] = p;
    if (t == 0) out[M] = E;
}

// Rank via LDS atomics; write packed (dl<<24)|src into bucket runs
// (~21 consecutive slots per (block,bucket) => line-coalesced scatter).
__global__ void scatter_kernel(const int* __restrict__ src, const int* __restrict__ dst,
                               const int* __restrict__ hist, const int* __restrict__ Tscan,
                               int* __restrict__ staged, int E, int NBKT) {
    __shared__ int lbase[NBKT_MAX];
    __shared__ int lcur[NBKT_MAX];
    int t = threadIdx.x, blk = blockIdx.x;
    for (int b = t; b < NBKT; b += 512) {
        lbase[b] = hist[blk * NBKT + b] + Tscan[b];
        lcur[b] = 0;
    }
    __syncthreads();
    int e0 = blk * EPB;
    #pragma unroll
    for (int i = 0; i < 32; ++i) {
        int e = e0 + i * 512 + t;
        if (e < E) {
            int d = dst[e], s = src[e];
            int b = d >> BKT_SHIFT;
            int r = atomicAdd(&lcur[b], 1);
            staged[lbase[b] + r] = ((d & (BKT_NODES - 1)) << 24) | s;
        }
    }
}

// One block per bucket: LDS per-node count -> scan (writes rp!) -> LDS place
// -> coalesced col flush.
__global__ void fine_fill(const int* __restrict__ staged, const int* __restrict__ Tscan,
                          int* __restrict__ rp, int* __restrict__ col,
                          int N, int E, int NBKT) {
    __shared__ int scnt[256];   // 128 used; padded to 256 for uniform scan
    __shared__ int srel[256];
    __shared__ int scur[256];
    __shared__ int scol[SCOL_CAP];
    int b = blockIdx.x, t = threadIdx.x;
    int n0 = b << BKT_SHIFT;
    int nn = min(BKT_NODES, N - n0);
    int e0 = Tscan[b];
    int e1 = Tscan[b + 1];
    int m = e1 - e0;

    scnt[t] = 0; scur[t] = 0;
    __syncthreads();
    for (int i = t; i < m; i += 256) {
        int dl = ((unsigned)staged[e0 + i]) >> 24;
        atomicAdd(&scnt[dl], 1);
    }
    __syncthreads();
    int inc_in = scnt[t];
    for (int off = 1; off < 256; off <<= 1) {   // Hillis-Steele inclusive
        int add = (t >= off) ? scnt[t - off] : 0;
        __syncthreads();
        scnt[t] += add;
        __syncthreads();
    }
    int excl = scnt[t] - inc_in;
    srel[t] = excl;
    if (t < nn) rp[n0 + t] = e0 + excl;
    if (b == NBKT - 1 && t == 0) rp[N] = E;
    __syncthreads();

    if (m <= SCOL_CAP) {
        for (int i = t; i < m; i += 256) {
            int v = staged[e0 + i];
            int dl = ((unsigned)v) >> 24;
            int p = srel[dl] + atomicAdd(&scur[dl], 1);
            scol[p] = v & 0xFFFFFF;
        }
        __syncthreads();
        for (int i = t; i < m; i += 256) col[e0 + i] = scol[i];
    } else {  // statistically unreachable overflow fallback
        for (int i = t; i < m; i += 256) {
            int v = staged[e0 + i];
            int dl = ((unsigned)v) >> 24;
            int p = srel[dl] + atomicAdd(&scur[dl], 1);
            col[e0 + p] = v & 0xFFFFFF;
        }
    }
}

// ---- Fused aggregate + MLP ---------------------------------------------
// Block = 256 threads = 16 nodes x 16 lanes; each lane handles 2 channels via
// packed-bf16 uint loads => one gather instruction serves 4 edges (4 nodes/wave).
// Block's contiguous col range prefetched to LDS: gathers never wait on col
// global loads (R6 bound: col->gather vmcnt chain at 1 inst/edge).

template <bool RELU_OUT, bool OUT_BF16>
__global__ void agg_mlp(const ushort_t* __restrict__ xin, const int* __restrict__ rp,
                        const int* __restrict__ col,
                        const float* __restrict__ Wa, const float* __restrict__ ba,
                        const float* __restrict__ Wb, const float* __restrict__ bb,
                        void* __restrict__ outv, int N) {
    __shared__ float sWa[32 * 16];
    __shared__ float sWb[16 * 32];
    __shared__ float sba[16], sbb[32];
    __shared__ float sv[NPB][32];
    __shared__ float st1[NPB][16];
    __shared__ int scol[SCOL_N];

    int t = threadIdx.x;
    sWa[t] = Wa[t];  sWa[t + 256] = Wa[t + 256];
    sWb[t] = Wb[t];  sWb[t + 256] = Wb[t + 256];
    if (t < 16) sba[t] = ba[t];
    if (t < 32) sbb[t] = bb[t];

    int base = blockIdx.x * NPB;
    int kb = rp[base];
    int kt = rp[min(base + NPB, N)];
    int tot = kt - kb;
    bool ovf = (tot > SCOL_N);
    if (!ovf) {
        for (int i = t; i < tot; i += 256) scol[i] = col[kb + i];
    }
    __syncthreads();

    int ln = t >> 4;          // node slot 0..15
    int sl = t & 15;          // channels 2*sl, 2*sl+1
    int n  = base + ln;
    bool act = (n < N);
    const uint_t* x32 = (const uint_t*)xin;   // row = 16 uints (32 bf16)

    if (act) {
        uint_t us = x32[(size_t)n * 16 + sl];
        float vx = __uint_as_float(us << 16);
        float vy = __uint_as_float(us & 0xFFFF0000u);
        int ks = rp[n], ke = rp[n + 1];
        if (!ovf) {
            int k = ks - kb, kend = ke - kb;
            for (; k + 8 <= kend; k += 8) {
                int s0 = scol[k + 0], s1 = scol[k + 1], s2 = scol[k + 2], s3 = scol[k + 3];
                int s4 = scol[k + 4], s5 = scol[k + 5], s6 = scol[k + 6], s7 = scol[k + 7];
                uint_t u0 = x32[(size_t)s0 * 16 + sl];
                uint_t u1 = x32[(size_t)s1 * 16 + sl];
                uint_t u2 = x32[(size_t)s2 * 16 + sl];
                uint_t u3 = x32[(size_t)s3 * 16 + sl];
                uint_t u4 = x32[(size_t)s4 * 16 + sl];
                uint_t u5 = x32[(size_t)s5 * 16 + sl];
                uint_t u6 = x32[(size_t)s6 * 16 + sl];
                uint_t u7 = x32[(size_t)s7 * 16 + sl];
                vx += ((__uint_as_float(u0 << 16) + __uint_as_float(u1 << 16))
                     + (__uint_as_float(u2 << 16) + __uint_as_float(u3 << 16)))
                    + ((__uint_as_float(u4 << 16) + __uint_as_float(u5 << 16))
                     + (__uint_as_float(u6 << 16) + __uint_as_float(u7 << 16)));
                vy += ((__uint_as_float(u0 & 0xFFFF0000u) + __uint_as_float(u1 & 0xFFFF0000u))
                     + (__uint_as_float(u2 & 0xFFFF0000u) + __uint_as_float(u3 & 0xFFFF0000u)))
                    + ((__uint_as_float(u4 & 0xFFFF0000u) + __uint_as_float(u5 & 0xFFFF0000u))
                     + (__uint_as_float(u6 & 0xFFFF0000u) + __uint_as_float(u7 & 0xFFFF0000u)));
            }
            for (; k < kend; ++k) {
                uint_t u0 = x32[(size_t)scol[k] * 16 + sl];
                vx += __uint_as_float(u0 << 16);
                vy += __uint_as_float(u0 & 0xFFFF0000u);
            }
        } else {  // statistically unreachable
            for (int k = ks; k < ke; ++k) {
                uint_t u0 = x32[(size_t)col[k] * 16 + sl];
                vx += __uint_as_float(u0 << 16);
                vy += __uint_as_float(u0 & 0xFFFF0000u);
            }
        }
        sv[ln][2 * sl]     = vx;
        sv[ln][2 * sl + 1] = vy;
    }
    __syncthreads();

    if (act) {   // hidden unit sl for node ln
        float h = sba[sl];
        #pragma unroll
        for (int cc = 0; cc < 32; ++cc) h += sv[ln][cc] * sWa[cc * 16 + sl];
        st1[ln][sl] = fmaxf(h, 0.f);
    }
    __syncthreads();

    if (act) {   // out channels 2*sl, 2*sl+1 for node ln
        int c0 = 2 * sl;
        float a0 = sbb[c0], a1 = sbb[c0 + 1];
        #pragma unroll
        for (int j = 0; j < 16; ++j) {
            float hj = st1[ln][j];
            a0 += hj * sWb[j * 32 + c0];
            a1 += hj * sWb[j * 32 + c0 + 1];
        }
        if (RELU_OUT) { a0 = fmaxf(a0, 0.f); a1 = fmaxf(a1, 0.f); }
        if (OUT_BF16) {
            uint_t p = (uint_t)f2bf(a0) | ((uint_t)f2bf(a1) << 16);
            ((uint_t*)outv)[(size_t)n * 16 + sl] = p;
        } else {
            float2 o; o.x = a0; o.y = a1;
            ((float2*)outv)[(size_t)n * 16 + sl] = o;
        }
    }
}

// ---- Launch -------------------------------------------------------------

extern "C" void kernel_launch(void* const* d_in, const int* in_sizes, int n_in,
                              void* d_out, int out_size, void* d_ws, size_t ws_size,
                              hipStream_t stream) {
    const float* x  = (const float*)d_in[0];
    const int*   ei = (const int*)d_in[1];
    const float* W1 = (const float*)d_in[2];
    const float* b1 = (const float*)d_in[3];
    const float* W2 = (const float*)d_in[4];
    const float* b2 = (const float*)d_in[5];
    const float* W3 = (const float*)d_in[6];
    const float* b3 = (const float*)d_in[7];
    const float* W4 = (const float*)d_in[8];
    const float* b4 = (const float*)d_in[9];

    const int N = in_sizes[0] / 32;
    const int E = in_sizes[1] / 2;
    const int* src = ei;
    const int* dst = ei + E;

    const int NBKT = (N + BKT_NODES - 1) >> BKT_SHIFT;   // 782
    const int NBLK = (E + EPB - 1) / EPB;                // 153 (<=1024 for colscan)

    char* ws = (char*)d_ws;
    size_t o = 0;
    auto alloc = [&](size_t bytes) -> char* {
        o = (o + 255) & ~(size_t)255;
        char* r = ws + o;
        o += bytes;
        return r;
    };
    int*      hist   = (int*)     alloc(4 * (size_t)NBLK * NBKT);
    int*      T      = (int*)     alloc(4 * (size_t)NBKT);
    int*      Tscan  = (int*)     alloc(4 * (size_t)(NBKT + 1));
    int*      staged = (int*)     alloc(4 * (size_t)E);
    int*      rp     = (int*)     alloc(4 * (size_t)(N + 1));
    int*      col    = (int*)     alloc(4 * (size_t)E);
    ushort_t* xb     = (ushort_t*)alloc(2 * (size_t)N * 32);
    ushort_t* hb     = (ushort_t*)alloc(2 * (size_t)N * 32);

    int n4 = N * 32 / 4;
    to_bf16<<<(n4 + 255) / 256, 256, 0, stream>>>((const float4*)x, xb, n4);

    histA<<<NBLK, 512, 0, stream>>>(dst, hist, E, NBKT);
    colscan<<<NBKT, 256, 0, stream>>>(hist, T, NBLK, NBKT);
    scan_small<<<1, 1024, 0, stream>>>(T, Tscan, NBKT, E);
    scatter_kernel<<<NBLK, 512, 0, stream>>>(src, dst, hist, Tscan, staged, E, NBKT);
    fine_fill<<<NBKT, 256, 0, stream>>>(staged, Tscan, rp, col, N, E, NBKT);

    agg_mlp<true,  true ><<<(N + NPB - 1) / NPB, 256, 0, stream>>>(xb, rp, col,
                                                                   W1, b1, W2, b2, hb, N);
    agg_mlp<false, false><<<(N + NPB - 1) / NPB, 256, 0, stream>>>(hb, rp, col,
                                                                   W3, b3, W4, b4, d_out, N);
}